// Round 5
// baseline (384.988 us; speedup 1.0000x reference)
//
#include <hip/hip_runtime.h>
#include <cstdint>
#include <cstddef>

// Problem constants (fixed by reference).
#define BATCH 16
#define SEQ   4096
#define NS    512
#define TLAG  128            // truncation: ||A^128|| ~ 1e-5 -> error ~1e-4 << bf16 noise
#define PADR  128            // zero left-pad rows in padded x buffer
#define PS    (SEQ + PADR)   // 4224 padded rows per batch
#define CTILE 128            // conv time-tile rows per block
#define XROWS (CTILE + TLAG - 1)   // 255 staged rows
#define XSTR  72             // LDS row stride in u16 (144 B = 9*16B)
#define BLK   32768          // one 64x512 row-block in u16 (64*512)

typedef unsigned short u16;
typedef unsigned int   u32;
typedef short bf16x8 __attribute__((ext_vector_type(8)));   // 8 bf16 = 4 VGPRs
typedef float f32x4  __attribute__((ext_vector_type(4)));   // MFMA accumulator

__device__ __forceinline__ u16 f2bf(float f) {
    u32 u = __builtin_bit_cast(u32, f);
    return (u16)((u + 0x7FFFu + ((u >> 16) & 1u)) >> 16);   // RNE
}
__device__ __forceinline__ float bf2f(u16 h) {
    return __builtin_bit_cast(float, (u32)h << 16);
}

// ---------------------------------------------------------------------------
// gemm_tile: one 64(M)x64(N) output tile, K=512, bf16 in / fp32 acc / bf16
// out. Aop row-major [64][512]; bT [N_total][512] (operand-B transposed), n0
// selects the 64-col slice. oRM row-major out via LDS bounce; oT transposed
// out (absolute row rowT). Plain cached stores. block = 256 (4 waves x 16
// rows). Verified rounds 0-4. Leading sync in bounce path guards LDS reuse
// across sequential calls within one kernel.
// ---------------------------------------------------------------------------
__device__ __forceinline__ void gemm_tile(const u16* __restrict__ apM,
                                          const u16* __restrict__ bT, int n0,
                                          u16* __restrict__ oRM,
                                          u16* __restrict__ oT, int rowT,
                                          u16* __restrict__ lds)
{
    const int tid = threadIdx.x;
    const int w = tid >> 6, l = tid & 63;
    const int lr = l & 15, q8 = (l >> 4) * 8;

    const u16* ap  = apM + (size_t)(w * 16 + lr) * NS + q8;
    const u16* bp0 = bT  + (size_t)(n0 + lr) * NS + q8;

    f32x4 acc[4];
    const f32x4 zero = {0.f, 0.f, 0.f, 0.f};
    #pragma unroll
    for (int nt = 0; nt < 4; ++nt) acc[nt] = zero;

    #pragma unroll 4
    for (int ks = 0; ks < 16; ++ks) {
        const bf16x8 a = *(const bf16x8*)(ap + ks * 32);
        #pragma unroll
        for (int nt = 0; nt < 4; ++nt) {
            const bf16x8 bfr = *(const bf16x8*)(bp0 + (size_t)nt * 16 * NS + ks * 32);
            acc[nt] = __builtin_amdgcn_mfma_f32_16x16x32_bf16(a, bfr, acc[nt], 0, 0, 0);
        }
    }

    const int rr = (l >> 4) * 4;    // C/D: row = (lane>>4)*4 + reg, col = lane&15
    if (oT) {
        #pragma unroll
        for (int nt = 0; nt < 4; ++nt) {
            const int col = n0 + nt * 16 + lr;
            ushort4 pk;
            pk.x = f2bf(acc[nt][0]); pk.y = f2bf(acc[nt][1]);
            pk.z = f2bf(acc[nt][2]); pk.w = f2bf(acc[nt][3]);
            *(ushort4*)(oT + (size_t)col * NS + rowT + w * 16 + rr) = pk;
        }
    }
    if (oRM) {
        __syncthreads();   // previous tile's bounce readers must be done
        #pragma unroll
        for (int nt = 0; nt < 4; ++nt)
            #pragma unroll
            for (int r = 0; r < 4; ++r)
                lds[(w * 16 + rr + r) * 72 + nt * 16 + lr] = f2bf(acc[nt][r]);
        __syncthreads();
        const int r  = tid >> 2;             // 0..63
        const int c0 = (tid & 3) * 16;       // 0,16,32,48
        #pragma unroll
        for (int k = 0; k < 4; ++k) {
            const ushort4 q = *(const ushort4*)&lds[r * 72 + c0 + k * 4];
            *(ushort4*)(oRM + (size_t)r * NS + n0 + c0 + k * 4) = q;
        }
    }
}

// ---------------------------------------------------------------------------
// g_tile: G_m via G^T = R_q^T x L_r. ap0 = R^T (RM [64][512]), bT0 = L_r
// (RM [64][512]). Epilogue: bounce to lds[o][i], B-fragment swizzle read,
// D fold (m==0), store to Gsw. Verified round 4.
// ---------------------------------------------------------------------------
__device__ __forceinline__ void g_tile(const u16* __restrict__ ap0,
                                       const u16* __restrict__ bT0, int m,
                                       const float* __restrict__ D,
                                       u16* __restrict__ Gsw,
                                       u16* __restrict__ lds)
{
    const int tid = threadIdx.x;
    const int w = tid >> 6, l = tid & 63;
    const int lr = l & 15, q8 = (l >> 4) * 8;

    const u16* ap  = ap0 + (size_t)(w * 16 + lr) * NS + q8;
    const u16* bp0 = bT0 + (size_t)lr * NS + q8;

    f32x4 acc[4];
    const f32x4 zero = {0.f, 0.f, 0.f, 0.f};
    #pragma unroll
    for (int nt = 0; nt < 4; ++nt) acc[nt] = zero;

    #pragma unroll 4
    for (int ks = 0; ks < 16; ++ks) {
        const bf16x8 a = *(const bf16x8*)(ap + ks * 32);
        #pragma unroll
        for (int nt = 0; nt < 4; ++nt) {
            const bf16x8 bfr = *(const bf16x8*)(bp0 + (size_t)nt * 16 * NS + ks * 32);
            acc[nt] = __builtin_amdgcn_mfma_f32_16x16x32_bf16(a, bfr, acc[nt], 0, 0, 0);
        }
    }

    const int rr = (l >> 4) * 4;
    __syncthreads();   // guard LDS reuse across calls
    #pragma unroll
    for (int nt = 0; nt < 4; ++nt)       // lds[o][i] = f2bf(G_m[o][i])
        #pragma unroll
        for (int rk = 0; rk < 4; ++rk)
            lds[(nt * 16 + lr) * 72 + (w * 16 + rr + rk)] = f2bf(acc[nt][rk]);
    __syncthreads();

    const int f = tid >> 6;              // 0..3
    #pragma unroll
    for (int f2 = 0; f2 < 8; f2 += 4) {  // fragments f and f+4
        const int fi = f2 + f;
        const int ks = fi >> 2, nt = fi & 3;
        const int o  = nt * 16 + (l & 15);
        const int i0 = ks * 32 + (l >> 4) * 8;
        u16 v[8];
        #pragma unroll
        for (int j = 0; j < 8; ++j) {
            u16 gv = lds[o * 72 + i0 + j];
            if (m == 0) gv = f2bf(bf2f(gv) + D[o * 64 + i0 + j]);
            v[j] = gv;
        }
        ushort4 p0; p0.x = v[0]; p0.y = v[1]; p0.z = v[2]; p0.w = v[3];
        ushort4 p1; p1.x = v[4]; p1.y = v[5]; p1.z = v[6]; p1.w = v[7];
        u16* dst = Gsw + ((size_t)(m * 8 + fi) * 64 + l) * 8;
        *(ushort4*)(dst + 0) = p0;
        *(ushort4*)(dst + 4) = p1;
    }
}

// ---------------------------------------------------------------------------
// gbar: fence-free group barrier. Relaxed agent atomics execute at the
// coherent point; __syncthreads() first (drains vmcnt -> all prior cached
// stores committed to this XCD's L2, visible to the group). One fresh
// counter per (group, level); zeroed by hipMemsetAsync each run.
// ---------------------------------------------------------------------------
__device__ __forceinline__ void gbar(u32* __restrict__ f, u32 n)
{
    __syncthreads();
    if (threadIdx.x == 0) {
        __hip_atomic_fetch_add(f, 1u, __ATOMIC_RELAXED, __HIP_MEMORY_SCOPE_AGENT);
        while (__hip_atomic_load(f, __ATOMIC_RELAXED, __HIP_MEMORY_SCOPE_AGENT) < n)
            __builtin_amdgcn_s_sleep(2);
    }
    __syncthreads();
}

__device__ __forceinline__ int cnt_owned(int LG, int NG, int bit) {
    int c = 0;
    for (int q = LG; q < 8; q += NG) if (q & bit) ++c;
    return c;
}
__device__ __forceinline__ int nth_owned(int LG, int NG, int bit, int i) {
    int c = 0;
    for (int q = LG; q < 8; q += NG)
        if (q & bit) { if (c == i) return q; ++c; }
    return 0;
}

// Per-group arena offsets (u16 units).
#define AO_ARM    0
#define AO_AT     262144
#define AO_A2RM   524288
#define AO_A2T    786432
#define AO_A4RM   1048576
#define AO_A4T    1310720
#define AO_A8RM   1572864
#define AO_A8T    1835008
#define AO_A16RM  2097152
#define AO_A16T   2359296
#define AO_A32RM  2621440
#define AO_A32T   2883584
#define AO_A64RM  3145728
#define AO_L      3407872   // 16 x 32768
#define AO_RT0    3932160   // 32768
#define AO_RTX    3964928   // 8 q x 3 slots x 32768
#define ARENA_U16 4751360   // 9,502,720 B per group

// ---------------------------------------------------------------------------
// chain_kernel: ONE launch for the entire setup. 256 blocks self-organize
// into per-XCD groups via s_getreg(HW_REG_XCC_ID) + atomic census (coherent
// point, replay-safe: flags pre-zeroed by hipMemsetAsync). Each group
// REDUNDANTLY computes the squaring/L/R chain into its PRIVATE arena ->
// producer and consumer always share one XCD L2 -> plain cached stores +
// fence-free barriers are coherent (fresh-buffer discipline: every buffer
// written once, read only after its level's barrier; no address ever read
// before written -> no stale L1/L2 lines). Zero cross-XCD data flow; Gsw
// m-slices are disjoint per group and consumed by the NEXT kernel (kernel
// boundary = device-scope release, proven rounds 0/4). Logical group ids
// are elected from the census so ANY block->XCD distribution is correct.
// Math identical to round-4 verified chain -> y bit-identical.
// ---------------------------------------------------------------------------
__global__ __launch_bounds__(256, 1) void chain_kernel(const float* __restrict__ x,
                                                       const float* __restrict__ A,
                                                       const float* __restrict__ B,
                                                       const float* __restrict__ C,
                                                       const float* __restrict__ D,
                                                       u16* __restrict__ xbf,
                                                       u16* __restrict__ arenas,
                                                       u16* __restrict__ Gsw,
                                                       u32* __restrict__ flg)
{
    __shared__ u16 lds[64 * 72];
    __shared__ u32 sm[4];
    const int tid = threadIdx.x;

    // ---- census arrive: physical XCD id + rank within group ----
    if (tid == 0) {
        u32 xcc;
        asm volatile("s_getreg_b32 %0, hwreg(HW_REG_XCC_ID)" : "=s"(xcc));
        xcc &= 7u;
        sm[0] = xcc;
        sm[1] = __hip_atomic_fetch_add(&flg[xcc], 1u,
                                       __ATOMIC_RELAXED, __HIP_MEMORY_SCOPE_AGENT);
    }
    __syncthreads();
    const int K = sm[0], R = sm[1];

    // ---- phase 0: x fp32 -> xbf bf16 (global partition; consumed by conv
    //      across the kernel boundary) — overlaps census propagation ----
    for (int vb = blockIdx.x; vb < 4224; vb += 256) {
        const int id = vb * 256 + tid;
        const int b   = id / (PS * 16);
        const int rem = id - b * (PS * 16);
        const int p   = rem >> 4;
        const int g   = id & 15;
        ushort4 o;
        if (p < PADR) {
            o.x = 0; o.y = 0; o.z = 0; o.w = 0;
        } else {
            const float4 v = *(const float4*)(x + ((size_t)b * SEQ + (p - PADR)) * 64 + g * 4);
            o.x = f2bf(v.x); o.y = f2bf(v.y); o.z = f2bf(v.z); o.w = f2bf(v.w);
        }
        *(ushort4*)(xbf + ((size_t)b * PS + p) * 64 + g * 4) = o;
    }

    // ---- census complete: poll sum (monotonic counters -> sum==256 means
    //      all adds visible; no release/acquire -> no L2 flushes) ----
    if (tid == 0) {
        for (;;) {
            u32 s = 0;
            #pragma unroll
            for (int j = 0; j < 8; ++j)
                s += __hip_atomic_load(&flg[j], __ATOMIC_RELAXED, __HIP_MEMORY_SCOPE_AGENT);
            if (s == 256u) break;
            __builtin_amdgcn_s_sleep(2);
        }
        u32 lg = 0, ng = 0, n = 0;
        for (int j = 0; j < 8; ++j) {
            const u32 cj = __hip_atomic_load(&flg[j], __ATOMIC_RELAXED, __HIP_MEMORY_SCOPE_AGENT);
            if (cj) { if (j < K) ++lg; ++ng; }
            if (j == K) n = cj;
        }
        sm[2] = n;
        sm[3] = lg | (ng << 8);
    }
    __syncthreads();
    const int N  = sm[2];
    const int LG = sm[3] & 255;     // logical group index (0..NG-1)
    const int NG = sm[3] >> 8;      // number of non-empty groups

    u16* Gb    = arenas + (size_t)K * ARENA_U16;
    u16* Arm   = Gb + AO_ARM;   u16* At   = Gb + AO_AT;
    u16* A2rm  = Gb + AO_A2RM;  u16* A2t  = Gb + AO_A2T;
    u16* A4rm  = Gb + AO_A4RM;  u16* A4t  = Gb + AO_A4T;
    u16* A8rm  = Gb + AO_A8RM;  u16* A8t  = Gb + AO_A8T;
    u16* A16rm = Gb + AO_A16RM; u16* A16t = Gb + AO_A16T;
    u16* A32rm = Gb + AO_A32RM; u16* A32t = Gb + AO_A32T;
    u16* A64rm = Gb + AO_A64RM;
    u16* Lg    = Gb + AO_L;
    u16* Rt0   = Gb + AO_RT0;
    u16* RtX   = Gb + AO_RTX;
    u32* gf    = flg + 16 + K * 8;

    // ---- group prep: A -> Arm/At, B -> Rt0 (=B^T), C -> L0 (group arena) --
    for (int c = R; c < 1408; c += N) {
        const int id = c * 256 + tid;
        if (id < 262144) {
            const int col = id & 511;
            const u16 v = f2bf(A[id]);
            Arm[id] = v;
            At[(size_t)col * 512 + (id >> 9)] = v;
        } else if (id < 294912) {
            const int i = id - 262144;
            Rt0[(size_t)(i & 63) * 512 + (i >> 6)] = f2bf(B[i]);
        } else {
            const int i = id - 294912;   // < 65536
            Lg[i] = f2bf(C[i]);
        }
    }
    gbar(gf + 0, N);

    // ---- levels 1..4: squaring A^(2h) + L[h..2h) = L[0..h) * A^h ----
    {
        const u16* sqA[4]  = {Arm, A2rm, A4rm, A8rm};
        const u16* sqT[4]  = {At,  A2t,  A4t,  A8t};
        u16* sqOR[4] = {A2rm, A4rm, A8rm, A16rm};
        u16* sqOT[4] = {A2t,  A4t,  A8t,  A16t};
        #pragma unroll 1
        for (int lvl = 0; lvl < 4; ++lvl) {
            const int h   = 1 << lvl;
            const int tot = 64 + 8 * h;
            for (int t = R; t < tot; t += N) {
                if (t < 64) {
                    const int mr = t >> 3, n0 = (t & 7) * 64;
                    gemm_tile(sqA[lvl] + (size_t)mr * BLK, sqT[lvl], n0,
                              sqOR[lvl] + (size_t)mr * BLK, sqOT[lvl], mr * 64, lds);
                } else {
                    const int tt = t - 64, j = tt >> 3, n0 = (tt & 7) * 64;
                    gemm_tile(Lg + (size_t)j * BLK, sqT[lvl], n0,
                              Lg + (size_t)(h + j) * BLK, nullptr, 0, lds);
                }
            }
            gbar(gf + 1 + lvl, N);
        }
    }

    // ---- level 5: A32 = A16*A16 ; R-mult by A16 for owned odd q ----
    {
        const int c1  = cnt_owned(LG, NG, 1);
        const int tot = 64 + 8 * c1;
        for (int t = R; t < tot; t += N) {
            if (t < 64) {
                const int mr = t >> 3, n0 = (t & 7) * 64;
                gemm_tile(A16rm + (size_t)mr * BLK, A16t, n0,
                          A32rm + (size_t)mr * BLK, A32t, mr * 64, lds);
            } else {
                const int tt = t - 64, n0 = (tt & 7) * 64;
                const int q = nth_owned(LG, NG, 1, tt >> 3);
                gemm_tile(Rt0, A16rm, n0,
                          RtX + ((size_t)q * 3 + 0) * BLK, nullptr, 0, lds);
            }
        }
        gbar(gf + 5, N);
    }

    // ---- level 6: A64 = A32*A32 (RM only) ; R-mult by A32 (owned q&2) ----
    {
        const int c2  = cnt_owned(LG, NG, 2);
        const int tot = 64 + 8 * c2;
        for (int t = R; t < tot; t += N) {
            if (t < 64) {
                const int mr = t >> 3, n0 = (t & 7) * 64;
                gemm_tile(A32rm + (size_t)mr * BLK, A32t, n0,
                          A64rm + (size_t)mr * BLK, nullptr, 0, lds);
            } else {
                const int tt = t - 64, n0 = (tt & 7) * 64;
                const int q = nth_owned(LG, NG, 2, tt >> 3);
                const u16* src = (q & 1) ? RtX + ((size_t)q * 3 + 0) * BLK : Rt0;
                gemm_tile(src, A32rm, n0,
                          RtX + ((size_t)q * 3 + 1) * BLK, nullptr, 0, lds);
            }
        }
        gbar(gf + 6, N);
    }

    // ---- level 7: R-mult by A64 (owned q&4) ----
    {
        const int c4  = cnt_owned(LG, NG, 4);
        for (int t = R; t < 8 * c4; t += N) {
            const int n0 = (t & 7) * 64;
            const int q = nth_owned(LG, NG, 4, t >> 3);
            const u16* src = (q & 2) ? RtX + ((size_t)q * 3 + 1) * BLK
                           : (q & 1) ? RtX + ((size_t)q * 3 + 0) * BLK : Rt0;
            gemm_tile(src, A64rm, n0,
                      RtX + ((size_t)q * 3 + 2) * BLK, nullptr, 0, lds);
        }
        gbar(gf + 7, N);
    }

    // ---- G: for each owned q, 16 lags m = 16q + r (disjoint Gsw slices) ----
    {
        const int nq = (8 - LG + NG - 1) / NG;
        for (int t = R; t < 16 * nq; t += N) {
            const int q = LG + (t >> 4) * NG;
            const int r = t & 15;
            const u16* rf = (q & 4) ? RtX + ((size_t)q * 3 + 2) * BLK
                          : (q & 2) ? RtX + ((size_t)q * 3 + 1) * BLK
                          : (q & 1) ? RtX + ((size_t)q * 3 + 0) * BLK : Rt0;
            g_tile(rf, Lg + (size_t)r * BLK, 16 * q + r, D, Gsw, lds);
        }
    }
}

// ---------------------------------------------------------------------------
// conv_kernel: y[b,t0+tau,o] = sum_m sum_i G_m[o][i] x[t0+tau-m][i].
// Round-5 change: G fragments staged ONCE per block into double-buffered
// LDS (pairs of lags, 16 KB/pair) instead of every wave re-loading the same
// 8 KB/lag from L1 (was ~2 GB of L1 traffic -> the 37%-MfmaUtil cap).
// Values & accumulation order per output element unchanged -> y bit-exact.
// ---------------------------------------------------------------------------
__global__ __launch_bounds__(256, 2) void conv_kernel(const u16* __restrict__ xbf,
                                                      const u16* __restrict__ gsw,
                                                      float* __restrict__ y)
{
    __shared__ u16 Xs[XROWS * XSTR];   // 36,720 B
    __shared__ uint4 Gs[2][1024];      // 32,768 B (2 x {2 lags x 8 frags x 64 lanes})

    const int tid = threadIdx.x;
    const int b  = blockIdx.y;
    const int t0 = blockIdx.x * CTILE;

    // Stage padded rows [t0+1 .. t0+255] (= times t0-127 .. t0+127) into LDS.
    {
        const int g = tid & 7;
        int r = tid >> 3;
        const u16* src = xbf + ((size_t)b * PS + t0 + 1) * 64 + g * 8;
        #pragma unroll
        for (int it = 0; it < 8; ++it, r += 32) {
            if (r < XROWS) {
                const uint4 v = *(const uint4*)(src + (size_t)r * 64);
                *(uint4*)&Xs[r * XSTR + g * 8] = v;
            }
        }
    }

    const uint4* gp4 = (const uint4*)gsw;
    uint4 st[4];
    #pragma unroll
    for (int j = 0; j < 4; ++j) st[j] = gp4[tid + j * 256];   // pair 0

    const int w    = tid >> 6;
    const int l    = tid & 63;
    const int lr   = l & 15;
    const int q8   = (l >> 4) * 8;
    const int wrow = w * 32;

    f32x4 acc[2][4];
    const f32x4 zero = {0.f, 0.f, 0.f, 0.f};
    #pragma unroll
    for (int mt = 0; mt < 2; ++mt)
        #pragma unroll
        for (int nt = 0; nt < 4; ++nt) acc[mt][nt] = zero;

    #pragma unroll
    for (int j = 0; j < 4; ++j) Gs[0][tid + j * 256] = st[j];
    __syncthreads();

    for (int p = 0; p < 64; ++p) {            // pair of lags {2p, 2p+1}
        const int cur = p & 1;
        if (p < 63) {
            #pragma unroll
            for (int j = 0; j < 4; ++j) st[j] = gp4[(p + 1) * 1024 + tid + j * 256];
        }
        #pragma unroll
        for (int sub = 0; sub < 2; ++sub) {
            const int m = 2 * p + sub;
            bf16x8 bc[8];
            #pragma unroll
            for (int f = 0; f < 8; ++f)
                bc[f] = __builtin_bit_cast(bf16x8, Gs[cur][sub * 512 + f * 64 + l]);

            const int rbase = wrow + lr + (TLAG - 1) - m;
            bf16x8 a[2][2];
            #pragma unroll
            for (int mt = 0; mt < 2; ++mt)
                #pragma unroll
                for (int ks = 0; ks < 2; ++ks)
                    a[mt][ks] = *(const bf16x8*)&Xs[(rbase + mt * 16) * XSTR + ks * 32 + q8];

            #pragma unroll
            for (int ks = 0; ks < 2; ++ks)
                #pragma unroll
                for (int mt = 0; mt < 2; ++mt)
                    #pragma unroll
                    for (int nt = 0; nt < 4; ++nt)
                        acc[mt][nt] = __builtin_amdgcn_mfma_f32_16x16x32_bf16(
                            a[mt][ks], bc[ks * 4 + nt], acc[mt][nt], 0, 0, 0);
        }
        if (p < 63) {
            #pragma unroll
            for (int j = 0; j < 4; ++j) Gs[cur ^ 1][tid + j * 256] = st[j];
        }
        __syncthreads();
    }

    // Epilogue: C/D layout col = lane&15 (out-feature), row = (lane>>4)*4+reg (time).
    const int rr = (l >> 4) * 4;
    #pragma unroll
    for (int mt = 0; mt < 2; ++mt) {
        #pragma unroll
        for (int nt = 0; nt < 4; ++nt) {
            const int t = t0 + wrow + mt * 16 + rr;
            const int o = nt * 16 + lr;
            float* yp = y + ((size_t)b * SEQ + t) * 64 + o;
            #pragma unroll
            for (int r = 0; r < 4; ++r) yp[(size_t)r * 64] = acc[mt][nt][r];
        }
    }
}

// ===========================================================================
// FALLBACK PATH (round-4 verified multi-launch chain) — used if ws_size is
// too small for the fused per-XCD arenas.
// ===========================================================================
__global__ __launch_bounds__(256) void prep_all(const float* __restrict__ x,
                                                const float* __restrict__ A,
                                                const float* __restrict__ B,
                                                const float* __restrict__ C,
                                                u16* __restrict__ xbf,
                                                u16* __restrict__ Arm,
                                                u16* __restrict__ At,
                                                u16* __restrict__ Rt,
                                                u16* __restrict__ L)
{
    const int bid = blockIdx.x;
    if (bid < 4224) {
        const int id = bid * 256 + threadIdx.x;
        const int b   = id / (PS * 16);
        const int rem = id - b * (PS * 16);
        const int p   = rem >> 4;
        const int g   = id & 15;
        ushort4 o;
        if (p < PADR) {
            o.x = 0; o.y = 0; o.z = 0; o.w = 0;
        } else {
            const float4 v = *(const float4*)(x + ((size_t)b * SEQ + (p - PADR)) * 64 + g * 4);
            o.x = f2bf(v.x); o.y = f2bf(v.y); o.z = f2bf(v.z); o.w = f2bf(v.w);
        }
        *(ushort4*)(xbf + ((size_t)b * PS + p) * 64 + g * 4) = o;
    } else {
        const int id = (bid - 4224) * 256 + threadIdx.x;
        if (id < 262144) {
            const int c = id & 511;
            const u16 v = f2bf(A[id]);
            Arm[id] = v;
            At[(size_t)c * 512 + (id >> 9)] = v;
        } else if (id < 262144 + 32768) {
            const int i = id - 262144;
            Rt[(size_t)(i & 63) * 512 + (i >> 6)] = f2bf(B[i]);
        } else if (id < 262144 + 65536) {
            const int i = id - 262144 - 32768;
            L[i] = f2bf(C[i]);
        }
    }
}

__global__ __launch_bounds__(256, 1) void stage_kernel(const u16* __restrict__ expAp,
                                                       const u16* __restrict__ expBT,
                                                       u16* __restrict__ expOut,
                                                       const u16* __restrict__ sqIn,
                                                       const u16* __restrict__ sqInT,
                                                       u16* __restrict__ sqOutRM,
                                                       u16* __restrict__ sqOutT,
                                                       int E)
{
    __shared__ u16 lds[64 * 72];
    const int t = blockIdx.x;
    if (t < E) {
        const int j = t >> 3, n0 = (t & 7) * 64;
        gemm_tile(expAp + (size_t)j * BLK, expBT, n0,
                  expOut + (size_t)j * BLK, nullptr, 0, lds);
    } else {
        const int tt = t - E;
        const int mr = tt >> 3, n0 = (tt & 7) * 64;
        gemm_tile(sqIn + (size_t)mr * BLK, sqInT, n0,
                  sqOutRM + (size_t)mr * BLK, sqOutT, mr * 64, lds);
    }
}

__global__ __launch_bounds__(256, 1) void g_kernel(const u16* __restrict__ Rt,
                                                   const u16* __restrict__ L,
                                                   const float* __restrict__ D,
                                                   u16* __restrict__ Gsw)
{
    __shared__ u16 lds[64 * 72];
    const int m = blockIdx.x;
    g_tile(Rt + (size_t)(m >> 4) * BLK, L + (size_t)(m & 15) * BLK, m, D, Gsw, lds);
}

// ---------------------------------------------------------------------------
// Fused workspace layout (bytes):
//   0           xbf      8,650,752
//   8,650,752   Gsw      1,048,576
//   9,699,328   flg            512   (census[8] + 8 groups x 8 level bars)
//   9,699,840   arenas  76,021,760   (8 x 9,502,720 per-XCD private arena)
//   total: 85,721,600
// ---------------------------------------------------------------------------
extern "C" void kernel_launch(void* const* d_in, const int* in_sizes, int n_in,
                              void* d_out, int out_size, void* d_ws, size_t ws_size,
                              hipStream_t stream)
{
    const float* x = (const float*)d_in[0];
    const float* A = (const float*)d_in[1];
    const float* B = (const float*)d_in[2];
    const float* C = (const float*)d_in[3];
    const float* D = (const float*)d_in[4];
    float* y = (float*)d_out;
    char* w = (char*)d_ws;

    const size_t WS_NEED_FUSED = 9699840ull + 8ull * 9502720ull;   // 85,721,600

    if (ws_size >= WS_NEED_FUSED) {
        u16* xbf    = (u16*)(w + 0);
        u16* Gsw    = (u16*)(w + 8650752);
        u32* flg    = (u32*)(w + 9699328);
        u16* arenas = (u16*)(w + 9699840);

        hipMemsetAsync(flg, 0, 512, stream);   // replay-safe census/barrier init
        chain_kernel<<<256, 256, 0, stream>>>(x, A, B, C, D, xbf, arenas, Gsw, flg);
        conv_kernel<<<dim3(SEQ / CTILE, BATCH), 256, 0, stream>>>(xbf, Gsw, y);
    } else {
        // round-4 verified multi-launch fallback
        u16* xbf   = (u16*)(w + 0);
        u16* Arm   = (u16*)(w + 8650752);
        u16* At    = (u16*)(w + 9175040);
        u16* A2rm  = (u16*)(w + 9699328);
        u16* A2t   = (u16*)(w + 10223616);
        u16* A4rm  = (u16*)(w + 10747904);
        u16* A4t   = (u16*)(w + 11272192);
        u16* A8rm  = (u16*)(w + 11796480);
        u16* A8t   = (u16*)(w + 12320768);
        u16* A16rm = (u16*)(w + 12845056);
        u16* A16t  = (u16*)(w + 13369344);
        u16* A32rm = (u16*)(w + 13893632);
        u16* A32t  = (u16*)(w + 14417920);
        u16* A64rm = (u16*)(w + 14942208);
        u16* L     = (u16*)(w + 15532032);
        u16* Rt    = (u16*)(w + 16580608);
        u16* Gsw   = (u16*)(w + 17104896);

        prep_all<<<5504, 256, 0, stream>>>(x, A, B, C, xbf, Arm, At, Rt, L);
        stage_kernel<<<72, 256, 0, stream>>>(L, At, L + 1 * BLK, Arm, At, A2rm, A2t, 8);
        stage_kernel<<<80, 256, 0, stream>>>(L, A2t, L + 2 * BLK, A2rm, A2t, A4rm, A4t, 16);
        stage_kernel<<<96, 256, 0, stream>>>(L, A4t, L + 4 * BLK, A4rm, A4t, A8rm, A8t, 32);
        stage_kernel<<<128, 256, 0, stream>>>(L, A8t, L + 8 * BLK, A8rm, A8t, A16rm, A16t, 64);
        stage_kernel<<<72, 256, 0, stream>>>(Rt, A16rm, Rt + 1 * BLK, A16rm, A16t, A32rm, A32t, 8);
        stage_kernel<<<80, 256, 0, stream>>>(Rt, A32rm, Rt + 2 * BLK, A32rm, A32t, A64rm, nullptr, 16);
        stage_kernel<<<32, 256, 0, stream>>>(Rt, A64rm, Rt + 4 * BLK, nullptr, nullptr, nullptr, nullptr, 32);
        g_kernel<<<128, 256, 0, stream>>>(Rt, L, D, Gsw);
        conv_kernel<<<dim3(SEQ / CTILE, BATCH), 256, 0, stream>>>(xbf, Gsw, y);
    }
}

// Round 6
// 235.288 us; speedup vs baseline: 1.6362x; 1.6362x over previous
//
#include <hip/hip_runtime.h>
#include <cstdint>
#include <cstddef>

// Problem constants (fixed by reference).
#define BATCH 16
#define SEQ   4096
#define NS    512
#define TLAG  128            // truncation: ||A^128|| ~ 1e-5 -> error ~1e-4 << bf16 noise
#define PADR  128            // zero left-pad rows in padded x buffer
#define PS    (SEQ + PADR)   // 4224 padded rows per batch
#define CTILE 128            // conv time-tile rows per block
#define XROWS (CTILE + TLAG - 1)   // 255 staged rows
#define XSTR  72             // LDS row stride in u16 (144 B = 9*16B)
#define BLK   32768          // one 64x512 row-block in u16 (64*512)

typedef unsigned short u16;
typedef unsigned int   u32;
typedef short bf16x8 __attribute__((ext_vector_type(8)));   // 8 bf16 = 4 VGPRs
typedef float f32x4  __attribute__((ext_vector_type(4)));   // MFMA accumulator

__device__ __forceinline__ u16 f2bf(float f) {
    u32 u = __builtin_bit_cast(u32, f);
    return (u16)((u + 0x7FFFu + ((u >> 16) & 1u)) >> 16);   // RNE
}
__device__ __forceinline__ float bf2f(u16 h) {
    return __builtin_bit_cast(float, (u32)h << 16);
}

// ---------------------------------------------------------------------------
// prep_all: one launch for all input conversion (round-4 verified).
//  blocks [0,4224):    x fp32 -> xbf bf16 (128 zero rows prepended per batch)
//  blocks [4224,5504): A -> Arm + At; B -> Rt[0] (= B^T); C -> L[0].
// ---------------------------------------------------------------------------
__global__ __launch_bounds__(256) void prep_all(const float* __restrict__ x,
                                                const float* __restrict__ A,
                                                const float* __restrict__ B,
                                                const float* __restrict__ C,
                                                u16* __restrict__ xbf,
                                                u16* __restrict__ Arm,
                                                u16* __restrict__ At,
                                                u16* __restrict__ Rt,
                                                u16* __restrict__ L)
{
    const int bid = blockIdx.x;
    if (bid < 4224) {
        const int id = bid * 256 + threadIdx.x;      // 16*4224*16 = 1,081,344
        const int b   = id / (PS * 16);
        const int rem = id - b * (PS * 16);
        const int p   = rem >> 4;
        const int g   = id & 15;
        ushort4 o;
        if (p < PADR) {
            o.x = 0; o.y = 0; o.z = 0; o.w = 0;
        } else {
            const float4 v = *(const float4*)(x + ((size_t)b * SEQ + (p - PADR)) * 64 + g * 4);
            o.x = f2bf(v.x); o.y = f2bf(v.y); o.z = f2bf(v.z); o.w = f2bf(v.w);
        }
        *(ushort4*)(xbf + ((size_t)b * PS + p) * 64 + g * 4) = o;
    } else {
        const int id = (bid - 4224) * 256 + threadIdx.x;   // 327,680 total
        if (id < 262144) {                                 // A: 512x512
            const int c = id & 511;
            const u16 v = f2bf(A[id]);
            Arm[id] = v;
            At[(size_t)c * 512 + (id >> 9)] = v;
        } else if (id < 262144 + 32768) {                  // B: 512x64 -> B^T (=R_0^T)
            const int i = id - 262144;
            Rt[(size_t)(i & 63) * 512 + (i >> 6)] = f2bf(B[i]);
        } else if (id < 262144 + 65536) {                  // C: 64x512 -> L_0
            const int i = id - 262144 - 32768;
            L[i] = f2bf(C[i]);
        }
    }
}

// ---------------------------------------------------------------------------
// gemm_tile: one 64(M)x64(N) output tile, K=512, bf16 in / fp32 acc / bf16
// out. Aop row-major [64][512]; bT [N_total][512] (operand-B transposed), n0
// selects the 64-col slice. oRM row-major out via LDS bounce; oT transposed
// out (absolute row rowT). Plain cached stores -- kernel boundaries provide
// coherence (rounds 0/4 proven). block = 256 (4 waves x 16 rows).
// ---------------------------------------------------------------------------
__device__ __forceinline__ void gemm_tile(const u16* __restrict__ apM,
                                          const u16* __restrict__ bT, int n0,
                                          u16* __restrict__ oRM,
                                          u16* __restrict__ oT, int rowT,
                                          u16* __restrict__ lds)
{
    const int tid = threadIdx.x;
    const int w = tid >> 6, l = tid & 63;
    const int lr = l & 15, q8 = (l >> 4) * 8;

    const u16* ap  = apM + (size_t)(w * 16 + lr) * NS + q8;
    const u16* bp0 = bT  + (size_t)(n0 + lr) * NS + q8;

    f32x4 acc[4];
    const f32x4 zero = {0.f, 0.f, 0.f, 0.f};
    #pragma unroll
    for (int nt = 0; nt < 4; ++nt) acc[nt] = zero;

    #pragma unroll 4
    for (int ks = 0; ks < 16; ++ks) {
        const bf16x8 a = *(const bf16x8*)(ap + ks * 32);
        #pragma unroll
        for (int nt = 0; nt < 4; ++nt) {
            const bf16x8 bfr = *(const bf16x8*)(bp0 + (size_t)nt * 16 * NS + ks * 32);
            acc[nt] = __builtin_amdgcn_mfma_f32_16x16x32_bf16(a, bfr, acc[nt], 0, 0, 0);
        }
    }

    const int rr = (l >> 4) * 4;    // C/D: row = (lane>>4)*4 + reg, col = lane&15
    if (oT) {
        #pragma unroll
        for (int nt = 0; nt < 4; ++nt) {
            const int col = n0 + nt * 16 + lr;
            ushort4 pk;
            pk.x = f2bf(acc[nt][0]); pk.y = f2bf(acc[nt][1]);
            pk.z = f2bf(acc[nt][2]); pk.w = f2bf(acc[nt][3]);
            *(ushort4*)(oT + (size_t)col * NS + rowT + w * 16 + rr) = pk;
        }
    }
    if (oRM) {
        #pragma unroll
        for (int nt = 0; nt < 4; ++nt)
            #pragma unroll
            for (int r = 0; r < 4; ++r)
                lds[(w * 16 + rr + r) * 72 + nt * 16 + lr] = f2bf(acc[nt][r]);
        __syncthreads();
        const int r  = tid >> 2;             // 0..63
        const int c0 = (tid & 3) * 16;       // 0,16,32,48
        #pragma unroll
        for (int k = 0; k < 4; ++k) {
            const ushort4 q = *(const ushort4*)&lds[r * 72 + c0 + k * 4];
            *(ushort4*)(oRM + (size_t)r * NS + n0 + c0 + k * 4) = q;
        }
    }
}

// ---------------------------------------------------------------------------
// stage_kernel: one doubling stage (round-4 verified). grid = E + (sq?64:0).
//  blocks [0,E):    expansion tiles: out[j] = Aop[j] x BTop-slice
//  blocks [E,E+64): squaring tiles: A^{2h} = A^h * A^h, RM (+T if sqOutT).
// ---------------------------------------------------------------------------
__global__ __launch_bounds__(256, 1) void stage_kernel(const u16* __restrict__ expAp,
                                                       const u16* __restrict__ expBT,
                                                       u16* __restrict__ expOut,
                                                       const u16* __restrict__ sqIn,
                                                       const u16* __restrict__ sqInT,
                                                       u16* __restrict__ sqOutRM,
                                                       u16* __restrict__ sqOutT,
                                                       int E)
{
    __shared__ u16 lds[64 * 72];   // 9,216 B bounce buffer
    const int t = blockIdx.x;
    if (t < E) {
        const int j = t >> 3, n0 = (t & 7) * 64;
        gemm_tile(expAp + (size_t)j * BLK, expBT, n0,
                  expOut + (size_t)j * BLK, nullptr, 0, lds);
    } else {
        const int tt = t - E;
        const int mr = tt >> 3, n0 = (tt & 7) * 64;
        gemm_tile(sqIn + (size_t)mr * BLK, sqInT, n0,
                  sqOutRM + (size_t)mr * BLK, sqOutT, mr * 64, lds);
    }
}

// ---------------------------------------------------------------------------
// g_kernel: G_m (m = blockIdx.x) via G^T = R_q^T x L_r (q=m>>4, r=m&15).
// Epilogue: bounce to lds[o][i], B-fragment swizzle read + D fold (m==0) +
// store to Gsw. Round-4 verified. grid = 128 blocks.
// ---------------------------------------------------------------------------
__global__ __launch_bounds__(256, 1) void g_kernel(const u16* __restrict__ Rt,
                                                   const u16* __restrict__ L,
                                                   const float* __restrict__ D,
                                                   u16* __restrict__ Gsw)
{
    __shared__ u16 lds[64 * 72];
    const int m = blockIdx.x;
    const int q = m >> 4, r = m & 15;
    const u16* ap0 = Rt + (size_t)q * BLK;
    const u16* bT0 = L  + (size_t)r * BLK;

    const int tid = threadIdx.x;
    const int w = tid >> 6, l = tid & 63;
    const int lr = l & 15, q8 = (l >> 4) * 8;

    const u16* ap  = ap0 + (size_t)(w * 16 + lr) * NS + q8;
    const u16* bp0 = bT0 + (size_t)lr * NS + q8;

    f32x4 acc[4];
    const f32x4 zero = {0.f, 0.f, 0.f, 0.f};
    #pragma unroll
    for (int nt = 0; nt < 4; ++nt) acc[nt] = zero;

    #pragma unroll 4
    for (int ks = 0; ks < 16; ++ks) {
        const bf16x8 a = *(const bf16x8*)(ap + ks * 32);
        #pragma unroll
        for (int nt = 0; nt < 4; ++nt) {
            const bf16x8 bfr = *(const bf16x8*)(bp0 + (size_t)nt * 16 * NS + ks * 32);
            acc[nt] = __builtin_amdgcn_mfma_f32_16x16x32_bf16(a, bfr, acc[nt], 0, 0, 0);
        }
    }

    // acc[nt][reg]: i (row) = w*16 + (l>>4)*4 + reg, o (col) = nt*16 + lr.
    const int rr = (l >> 4) * 4;
    #pragma unroll
    for (int nt = 0; nt < 4; ++nt)       // lds[o][i] = f2bf(G_m[o][i])
        #pragma unroll
        for (int rk = 0; rk < 4; ++rk)
            lds[(nt * 16 + lr) * 72 + (w * 16 + rr + rk)] = f2bf(acc[nt][rk]);
    __syncthreads();

    const int f = tid >> 6;              // 0..3
    #pragma unroll
    for (int f2 = 0; f2 < 8; f2 += 4) {  // fragments f and f+4
        const int fi = f2 + f;
        const int ks = fi >> 2, nt = fi & 3;
        const int o  = nt * 16 + (l & 15);
        const int i0 = ks * 32 + (l >> 4) * 8;
        u16 v[8];
        #pragma unroll
        for (int j = 0; j < 8; ++j) {
            u16 gv = lds[o * 72 + i0 + j];
            if (m == 0) gv = f2bf(bf2f(gv) + D[o * 64 + i0 + j]);
            v[j] = gv;
        }
        ushort4 p0; p0.x = v[0]; p0.y = v[1]; p0.z = v[2]; p0.w = v[3];
        ushort4 p1; p1.x = v[4]; p1.y = v[5]; p1.z = v[6]; p1.w = v[7];
        u16* dst = Gsw + ((size_t)(m * 8 + fi) * 64 + l) * 8;
        *(ushort4*)(dst + 0) = p0;
        *(ushort4*)(dst + 4) = p1;
    }
}

// ---------------------------------------------------------------------------
// conv_kernel: y[b,t0+tau,o] = sum_m sum_i G_m[o][i] x[t0+tau-m][i].
// Round-6 change (vs round-4's 78.5us/MfmaUtil 37%): G fragments staged
// ONCE per block into double-buffered LDS (pairs of lags, 16 KB/pair)
// instead of every wave re-loading the same 8 KB/lag through L1 (64 L1
// instr/CU/lag ~1024cy > 620cy MFMA issue -- the measured cap). Values &
// accumulation order per output element unchanged -> y bit-exact vs round 4
// (absmax must stay exactly 0.09375).
// ---------------------------------------------------------------------------
__global__ __launch_bounds__(256, 2) void conv_kernel(const u16* __restrict__ xbf,
                                                      const u16* __restrict__ gsw,
                                                      float* __restrict__ y)
{
    __shared__ u16 Xs[XROWS * XSTR];   // 36,720 B
    __shared__ uint4 Gs[2][1024];      // 32,768 B (2 x {2 lags x 8 frags x 64 lanes})

    const int tid = threadIdx.x;
    const int b  = blockIdx.y;
    const int t0 = blockIdx.x * CTILE;

    // Stage padded rows [t0+1 .. t0+255] (= times t0-127 .. t0+127) into LDS.
    {
        const int g = tid & 7;
        int r = tid >> 3;
        const u16* src = xbf + ((size_t)b * PS + t0 + 1) * 64 + g * 8;
        #pragma unroll
        for (int it = 0; it < 8; ++it, r += 32) {
            if (r < XROWS) {
                const uint4 v = *(const uint4*)(src + (size_t)r * 64);
                *(uint4*)&Xs[r * XSTR + g * 8] = v;
            }
        }
    }

    const uint4* gp4 = (const uint4*)gsw;
    uint4 st[4];
    #pragma unroll
    for (int j = 0; j < 4; ++j) st[j] = gp4[tid + j * 256];   // pair 0

    const int w    = tid >> 6;
    const int l    = tid & 63;
    const int lr   = l & 15;
    const int q8   = (l >> 4) * 8;
    const int wrow = w * 32;

    f32x4 acc[2][4];
    const f32x4 zero = {0.f, 0.f, 0.f, 0.f};
    #pragma unroll
    for (int mt = 0; mt < 2; ++mt)
        #pragma unroll
        for (int nt = 0; nt < 4; ++nt) acc[mt][nt] = zero;

    #pragma unroll
    for (int j = 0; j < 4; ++j) Gs[0][tid + j * 256] = st[j];
    __syncthreads();

    for (int p = 0; p < 64; ++p) {            // pair of lags {2p, 2p+1}
        const int cur = p & 1;
        if (p < 63) {
            #pragma unroll
            for (int j = 0; j < 4; ++j) st[j] = gp4[(p + 1) * 1024 + tid + j * 256];
        }
        #pragma unroll
        for (int sub = 0; sub < 2; ++sub) {
            const int m = 2 * p + sub;
            bf16x8 bc[8];
            #pragma unroll
            for (int f = 0; f < 8; ++f)
                bc[f] = __builtin_bit_cast(bf16x8, Gs[cur][sub * 512 + f * 64 + l]);

            const int rbase = wrow + lr + (TLAG - 1) - m;
            bf16x8 a[2][2];
            #pragma unroll
            for (int mt = 0; mt < 2; ++mt)
                #pragma unroll
                for (int ks = 0; ks < 2; ++ks)
                    a[mt][ks] = *(const bf16x8*)&Xs[(rbase + mt * 16) * XSTR + ks * 32 + q8];

            #pragma unroll
            for (int ks = 0; ks < 2; ++ks)
                #pragma unroll
                for (int mt = 0; mt < 2; ++mt)
                    #pragma unroll
                    for (int nt = 0; nt < 4; ++nt)
                        acc[mt][nt] = __builtin_amdgcn_mfma_f32_16x16x32_bf16(
                            a[mt][ks], bc[ks * 4 + nt], acc[mt][nt], 0, 0, 0);
        }
        if (p < 63) {
            #pragma unroll
            for (int j = 0; j < 4; ++j) Gs[cur ^ 1][tid + j * 256] = st[j];
        }
        __syncthreads();
    }

    // Epilogue: C/D layout col = lane&15 (out-feature), row = (lane>>4)*4+reg (time).
    const int rr = (l >> 4) * 4;
    #pragma unroll
    for (int mt = 0; mt < 2; ++mt) {
        #pragma unroll
        for (int nt = 0; nt < 4; ++nt) {
            const int t = t0 + wrow + mt * 16 + rr;
            const int o = nt * 16 + lr;
            float* yp = y + ((size_t)b * SEQ + t) * 64 + o;
            #pragma unroll
            for (int r = 0; r < 4; ++r) yp[(size_t)r * 64] = acc[mt][nt][r];
        }
    }
}

// ---------------------------------------------------------------------------
// Workspace layout (bytes, 16-aligned) — round-4 verified:
//   0           xbf     8,650,752   (16 x 4224 x 64 bf16)
//   8,650,752   Arm       524,288   (A row-major)
//   9,175,040   At        524,288   (A^T)
//   9,699,328   A2rm      524,288
//  10,223,616   A2t       524,288
//  10,747,904   A4rm      524,288
//  11,272,192   A4t       524,288
//  11,796,480   A8rm      524,288
//  12,320,768   A8t       524,288
//  12,845,056   A16rm     524,288
//  13,369,344   A16t      524,288
//  13,893,632   A32rm     524,288
//  14,417,920   A32t      524,288
//  14,942,208   A64rm     524,288
//  15,532,032   L       1,048,576   (L_r = C A^r, r<16, RM row-blocks)
//  16,580,608   Rt        524,288   (R_q^T = (A^{16q} B)^T, q<8)
//  17,104,896   Gsw     1,048,576   (B-fragment-swizzled conv kernels)
//  total: 18,153,472
// ---------------------------------------------------------------------------
extern "C" void kernel_launch(void* const* d_in, const int* in_sizes, int n_in,
                              void* d_out, int out_size, void* d_ws, size_t ws_size,
                              hipStream_t stream)
{
    const float* x = (const float*)d_in[0];
    const float* A = (const float*)d_in[1];
    const float* B = (const float*)d_in[2];
    const float* C = (const float*)d_in[3];
    const float* D = (const float*)d_in[4];
    float* y = (float*)d_out;

    char* w = (char*)d_ws;
    u16* xbf   = (u16*)(w + 0);
    u16* Arm   = (u16*)(w + 8650752);
    u16* At    = (u16*)(w + 9175040);
    u16* A2rm  = (u16*)(w + 9699328);
    u16* A2t   = (u16*)(w + 10223616);
    u16* A4rm  = (u16*)(w + 10747904);
    u16* A4t   = (u16*)(w + 11272192);
    u16* A8rm  = (u16*)(w + 11796480);
    u16* A8t   = (u16*)(w + 12320768);
    u16* A16rm = (u16*)(w + 12845056);
    u16* A16t  = (u16*)(w + 13369344);
    u16* A32rm = (u16*)(w + 13893632);
    u16* A32t  = (u16*)(w + 14417920);
    u16* A64rm = (u16*)(w + 14942208);
    u16* L     = (u16*)(w + 15532032);
    u16* Rt    = (u16*)(w + 16580608);
    u16* Gsw   = (u16*)(w + 17104896);

    prep_all<<<5504, 256, 0, stream>>>(x, A, B, C, xbf, Arm, At, Rt, L);

    // Stage 1: L[1] = L[0]*A           ; A2  = A*A        (8 + 64 blocks)
    stage_kernel<<<72, 256, 0, stream>>>(L, At, L + 1 * BLK,
                                         Arm, At, A2rm, A2t, 8);
    // Stage 2: L[2+j] = L[j]*A2, j<2   ; A4  = A2*A2      (16 + 64)
    stage_kernel<<<80, 256, 0, stream>>>(L, A2t, L + 2 * BLK,
                                         A2rm, A2t, A4rm, A4t, 16);
    // Stage 3: L[4+j] = L[j]*A4, j<4   ; A8  = A4*A4      (32 + 64)
    stage_kernel<<<96, 256, 0, stream>>>(L, A4t, L + 4 * BLK,
                                         A4rm, A4t, A8rm, A8t, 32);
    // Stage 4: L[8+j] = L[j]*A8, j<8   ; A16 = A8*A8      (64 + 64)
    stage_kernel<<<128, 256, 0, stream>>>(L, A8t, L + 8 * BLK,
                                          A8rm, A8t, A16rm, A16t, 64);
    // Stage 5: R[1]^T = R[0]^T*A16^T   ; A32 = A16*A16    (8 + 64)
    stage_kernel<<<72, 256, 0, stream>>>(Rt, A16rm, Rt + 1 * BLK,
                                         A16rm, A16t, A32rm, A32t, 8);
    // Stage 6: R[2+j]^T = R[j]^T*A32^T ; A64 = A32*A32 (RM only) (16 + 64)
    stage_kernel<<<80, 256, 0, stream>>>(Rt, A32rm, Rt + 2 * BLK,
                                         A32rm, A32t, A64rm, nullptr, 16);
    // Stage 7: R[4+j]^T = R[j]^T*A64^T, j<4                (32)
    stage_kernel<<<32, 256, 0, stream>>>(Rt, A64rm, Rt + 4 * BLK,
                                         nullptr, nullptr, nullptr, nullptr, 32);
    // Stage 8: G_m = L_r R_q, swizzled + D fold            (128)
    g_kernel<<<128, 256, 0, stream>>>(Rt, L, D, Gsw);

    conv_kernel<<<dim3(SEQ / CTILE, BATCH), 256, 0, stream>>>(xbf, Gsw, y);
}